// Round 6
// baseline (1335.298 us; speedup 1.0000x reference)
//
#include <hip/hip_runtime.h>

#define TH  0.3f
#define DEC 0.2f

// LDS layout (float offsets) — all 16B-aligned where vector-accessed
#define OFF_X    0        // 38*38 = 1444 (x, zero-padded border)
#define OFF_W1   1444     // 10*28 = 280  (repack: [oc][k*9+j], pad to 28)
#define OFF_B1   1724     // 30
#define OFF_W2   1756     // 100*28 = 2800 (repack: [oc][ic][k*9+j], pad 28)
#define OFF_B2   4556     // 30
#define OFF_LIF  4588     // 4
#define OFF_S    4592     // 10*20*20 = 4000 (pooled L1 spikes, padded border); h1 in epilogue
#define SMEM_N   8592     // 34,368 bytes

#define Z4 make_float4(0.f, 0.f, 0.f, 0.f)

__device__ __forceinline__ float spikef(float v) { return v > TH ? 1.f : 0.f; }

// LIF update of one float4 state M (k0..k2 in x,y,z; k3/hh-inner in w), drives D0..D2
#define LIF4(M, D0, D1, D2)                                            \
    {                                                                  \
        float inner_ = fmaf((M).x, lw0, fmaf((M).y, lw1, fmaf((M).z, lw2, lb))); \
        (M).x = ((M).x > TH ? 0.f : (M).x * DEC) + (D0);               \
        (M).y = ((M).y > TH ? 0.f : (M).y * DEC) + (D1);               \
        (M).z = ((M).z > TH ? 0.f : (M).z * DEC) + (D2);               \
        (M).w = ((M).w > TH ? 0.f : (M).w * DEC) + inner_;             \
    }

// stream 27 weights (float4 chunks, immediate consumption), ACC(k,r,c,w)
#define CONV27(WB, ACC)                                                      \
    do {                                                                     \
        float4 w4_;                                                          \
        _Pragma("unroll")                                                    \
        for (int j_ = 0; j_ < 27; ++j_) {                                    \
            if ((j_ & 3) == 0)                                               \
                w4_ = *reinterpret_cast<const float4*>(&sm[(WB) + j_]);      \
            const float wv_ = ((j_ & 3) == 0) ? w4_.x :                      \
                              ((j_ & 3) == 1) ? w4_.y :                      \
                              ((j_ & 3) == 2) ? w4_.z : w4_.w;               \
            const int k_ = j_ / 9, r_ = (j_ - k_ * 9) / 3,                   \
                      c_ = j_ - k_ * 9 - r_ * 3;                             \
            ACC(k_, r_, c_, wv_);                                            \
        }                                                                    \
    } while (0)

#define ACC_L1(K, R, C, W)                                   \
    d[0][K] = fmaf(xv[R][C],         (W), d[0][K]);          \
    d[1][K] = fmaf(xv[R][C + 1],     (W), d[1][K]);          \
    d[2][K] = fmaf(xv[R + 1][C],     (W), d[2][K]);          \
    d[3][K] = fmaf(xv[R + 1][C + 1], (W), d[3][K]);

#define ACC_L2(K, R, C, W)                                   \
    acc[0][K] = fmaf(sv[R][C],         (W), acc[0][K]);      \
    acc[1][K] = fmaf(sv[R][C + 1],     (W), acc[1][K]);      \
    acc[2][K] = fmaf(sv[R + 1][C],     (W), acc[2][K]);      \
    acc[3][K] = fmaf(sv[R + 1][C + 1], (W), acc[3][K]);

// ---- layer 1: one cell (18x18 pooled grid), conv from LDS-x, state by ref ----
__device__ __forceinline__ void l1cell(float* __restrict__ sm, int cell,
                                       float lw0, float lw1, float lw2, float lb,
                                       float4& s0, float4& s1, float4& s2, float4& s3)
{
    int oc  = cell / 324;
    int rem = cell - oc * 324;
    int hh  = rem / 18;
    int ww  = rem - hh * 18;
    int y0 = 2 * hh, x0 = 2 * ww;

    float xv[4][4];
#pragma unroll
    for (int r = 0; r < 4; ++r) {
        float2 a = *reinterpret_cast<const float2*>(&sm[OFF_X + (y0 + r) * 38 + x0]);
        float2 b = *reinterpret_cast<const float2*>(&sm[OFF_X + (y0 + r) * 38 + x0 + 2]);
        xv[r][0] = a.x; xv[r][1] = a.y; xv[r][2] = b.x; xv[r][3] = b.y;
    }
    float d[4][3];
    {
        float b0  = sm[OFF_B1 + oc];
        float b1v = sm[OFF_B1 + 10 + oc];
        float b2v = sm[OFF_B1 + 20 + oc];
#pragma unroll
        for (int p = 0; p < 4; ++p) { d[p][0] = b0; d[p][1] = b1v; d[p][2] = b2v; }
    }
    CONV27(OFF_W1 + oc * 28, ACC_L1);

    float ssum = 0.f;
    LIF4(s0, d[0][0], d[0][1], d[0][2]);
    ssum += spikef(s0.x) + spikef(s0.y) + spikef(s0.z) + spikef(s0.w);
    LIF4(s1, d[1][0], d[1][1], d[1][2]);
    ssum += spikef(s1.x) + spikef(s1.y) + spikef(s1.z) + spikef(s1.w);
    LIF4(s2, d[2][0], d[2][1], d[2][2]);
    ssum += spikef(s2.x) + spikef(s2.y) + spikef(s2.z) + spikef(s2.w);
    LIF4(s3, d[3][0], d[3][1], d[3][2]);
    ssum += spikef(s3.x) + spikef(s3.y) + spikef(s3.z) + spikef(s3.w);

    sm[OFF_S + oc * 400 + (hh + 1) * 20 + (ww + 1)] = ssum * 0.25f;
}

// ---- layer 2: one cell (9x9 grid), conv over S (LDS), state + h1 by ref ----
__device__ __forceinline__ void l2cell(const float* __restrict__ sm, int cell,
                                       float lw0, float lw1, float lw2, float lb,
                                       float4& s0, float4& s1, float4& s2, float4& s3,
                                       float& h0, float& h1, float& h2, float& h3)
{
    int oc  = cell / 81;
    int rem = cell - oc * 81;
    int hh  = rem / 9;
    int ww  = rem - hh * 9;
    int y0 = 2 * hh, x0 = 2 * ww;

    float acc[4][3];
    {
        float b20 = 4.f * sm[OFF_B2 + oc];
        float b21 = 4.f * sm[OFF_B2 + 10 + oc];
        float b22 = 4.f * sm[OFF_B2 + 20 + oc];
#pragma unroll
        for (int p = 0; p < 4; ++p) { acc[p][0] = b20; acc[p][1] = b21; acc[p][2] = b22; }
    }

    const int sb = OFF_S + y0 * 20 + x0;      // even -> float2 aligned
    const int wb = OFF_W2 + (oc * 10) * 28;   // 16B aligned

    for (int ic = 0; ic < 10; ++ic) {
        float sv[4][4];
#pragma unroll
        for (int r = 0; r < 4; ++r) {
            float2 a = *reinterpret_cast<const float2*>(&sm[sb + ic * 400 + r * 20]);
            float2 b = *reinterpret_cast<const float2*>(&sm[sb + ic * 400 + r * 20 + 2]);
            sv[r][0] = a.x; sv[r][1] = a.y; sv[r][2] = b.x; sv[r][3] = b.y;
        }
        CONV27(wb + ic * 28, ACC_L2);
    }

    LIF4(s0, acc[0][0], acc[0][1], acc[0][2]);
    h0 += spikef(s0.x) * 0.25f; h1 += spikef(s0.y) * 0.25f;
    h2 += spikef(s0.z) * 0.25f; h3 += spikef(s0.w) * 0.25f;
    LIF4(s1, acc[1][0], acc[1][1], acc[1][2]);
    h0 += spikef(s1.x) * 0.25f; h1 += spikef(s1.y) * 0.25f;
    h2 += spikef(s1.z) * 0.25f; h3 += spikef(s1.w) * 0.25f;
    LIF4(s2, acc[2][0], acc[2][1], acc[2][2]);
    h0 += spikef(s2.x) * 0.25f; h1 += spikef(s2.y) * 0.25f;
    h2 += spikef(s2.z) * 0.25f; h3 += spikef(s2.w) * 0.25f;
    LIF4(s3, acc[3][0], acc[3][1], acc[3][2]);
    h0 += spikef(s3.x) * 0.25f; h1 += spikef(s3.y) * 0.25f;
    h2 += spikef(s3.z) * 0.25f; h3 += spikef(s3.w) * 0.25f;
}

__attribute__((amdgpu_waves_per_eu(2, 2)))
__global__ __launch_bounds__(512)
void scnn_kernel(const float* __restrict__ x,
                 const float* __restrict__ w1, const float* __restrict__ b1,
                 const float* __restrict__ w2, const float* __restrict__ b2,
                 const float* __restrict__ lif_w, const float* __restrict__ lif_b,
                 const float* __restrict__ fc_w, const float* __restrict__ fc_b,
                 const float* __restrict__ task_w, const float* __restrict__ task_b,
                 const int* __restrict__ tw_ptr,
                 float* __restrict__ out)
{
    __shared__ float sm[SMEM_N];
    const int tid = threadIdx.x;
    const int b   = blockIdx.x;
    const int T   = tw_ptr[0];

    for (int i = tid; i < SMEM_N; i += 512) sm[i] = 0.f;
    __syncthreads();

    for (int i = tid; i < 1296; i += 512) {
        int h = i / 36, w = i - h * 36;
        sm[OFF_X + (h + 1) * 38 + (w + 1)] = x[b * 1296 + i];
    }
    if (tid < 270) { // w1 (3,10,1,3,3) -> [oc][k*9+j] pad 28
        int k = tid / 90, r = tid - k * 90;
        int oc = r / 9, j = r - oc * 9;
        sm[OFF_W1 + oc * 28 + k * 9 + j] = w1[tid];
    }
    if (tid < 30)  sm[OFF_B1 + tid] = b1[tid];
    for (int i = tid; i < 2700; i += 512) { // w2 (3,10,10,3,3) -> [oc][ic][k*9+j] pad 28
        int k = i / 900, r1 = i - k * 900;
        int oc = r1 / 90, r2 = r1 - oc * 90;
        int ic = r2 / 9,  j  = r2 - ic * 9;
        sm[OFF_W2 + (oc * 10 + ic) * 28 + k * 9 + j] = w2[i];
    }
    if (tid < 30)  sm[OFF_B2 + tid] = b2[tid];
    if (tid < 3)   sm[OFF_LIF + tid] = lif_w[tid];
    if (tid == 0)  sm[OFF_LIF + 3] = lif_b[0];
    __syncthreads();

    const float lw0 = sm[OFF_LIF + 0], lw1 = sm[OFF_LIF + 1],
                lw2 = sm[OFF_LIF + 2], lb  = sm[OFF_LIF + 3];

    // ---- ALL recurrent state as named registers (no arrays -> no spill) ----
    float4 mA0=Z4,mA1=Z4,mA2=Z4,mA3=Z4;   // L1 cell tid
    float4 mB0=Z4,mB1=Z4,mB2=Z4,mB3=Z4;   // L1 cell tid+512
    float4 mC0=Z4,mC1=Z4,mC2=Z4,mC3=Z4;   // +1024
    float4 mD0=Z4,mD1=Z4,mD2=Z4,mD3=Z4;   // +1536
    float4 mE0=Z4,mE1=Z4,mE2=Z4,mE3=Z4;   // +2048
    float4 mF0=Z4,mF1=Z4,mF2=Z4,mF3=Z4;   // +2560
    float4 mG0=Z4,mG1=Z4,mG2=Z4,mG3=Z4;   // +3072 (tid<168)
    float4 mP0=Z4,mP1=Z4,mP2=Z4,mP3=Z4;   // L2 cell tid
    float4 mQ0=Z4,mQ1=Z4,mQ2=Z4,mQ3=Z4;   // L2 cell tid+512 (tid<298)
    float hA0=0.f,hA1=0.f,hA2=0.f,hA3=0.f;
    float hB0=0.f,hB1=0.f,hB2=0.f,hB3=0.f;

    for (int t = 0; t < T; ++t) {
        l1cell(sm, tid,        lw0, lw1, lw2, lb, mA0, mA1, mA2, mA3);
        l1cell(sm, tid +  512, lw0, lw1, lw2, lb, mB0, mB1, mB2, mB3);
        l1cell(sm, tid + 1024, lw0, lw1, lw2, lb, mC0, mC1, mC2, mC3);
        l1cell(sm, tid + 1536, lw0, lw1, lw2, lb, mD0, mD1, mD2, mD3);
        l1cell(sm, tid + 2048, lw0, lw1, lw2, lb, mE0, mE1, mE2, mE3);
        l1cell(sm, tid + 2560, lw0, lw1, lw2, lb, mF0, mF1, mF2, mF3);
        if (tid < 3240 - 3072)
            l1cell(sm, tid + 3072, lw0, lw1, lw2, lb, mG0, mG1, mG2, mG3);
        __syncthreads();

        l2cell(sm, tid, lw0, lw1, lw2, lb, mP0, mP1, mP2, mP3, hA0, hA1, hA2, hA3);
        if (tid < 810 - 512)
            l2cell(sm, tid + 512, lw0, lw1, lw2, lb, mQ0, mQ1, mQ2, mQ3, hB0, hB1, hB2, hB3);
        __syncthreads();
    }

    // ---- epilogue: h1 -> LDS (overwrites S), FC(50x3240), task heads ----
    *reinterpret_cast<float4*>(&sm[OFF_S + tid * 4]) = make_float4(hA0, hA1, hA2, hA3);
    if (tid < 810 - 512)
        *reinterpret_cast<float4*>(&sm[OFF_S + (tid + 512) * 4]) = make_float4(hB0, hB1, hB2, hB3);
    __syncthreads();

    float invT = 1.f / (float)T;
    int f = tid >> 3, g = tid & 7;
    if (f < 50) {
        const float* wrow = fc_w + f * 3240;
        float p0 = 0.f, p1 = 0.f;
        for (int j = g; j < 3240; j += 16) {
            p0 = fmaf(sm[OFF_S + j], wrow[j], p0);
            if (j + 8 < 3240) p1 = fmaf(sm[OFF_S + j + 8], wrow[j + 8], p1);
        }
        float p = p0 + p1;
        p += __shfl_xor(p, 1);
        p += __shfl_xor(p, 2);
        p += __shfl_xor(p, 4);
        if (g == 0) sm[OFF_X + f] = p * invT + fc_b[f];
    }
    __syncthreads();

    if (tid < 30) {
        float acc = task_b[tid];
        const float* twp = task_w + tid * 50;
        for (int j = 0; j < 50; ++j) acc = fmaf(sm[OFF_X + j], twp[j], acc);
        out[b * 30 + tid] = acc;
    }
}

extern "C" void kernel_launch(void* const* d_in, const int* in_sizes, int n_in,
                              void* d_out, int out_size, void* d_ws, size_t ws_size,
                              hipStream_t stream) {
    const float* x      = (const float*)d_in[0];
    const float* w1     = (const float*)d_in[1];
    const float* b1     = (const float*)d_in[2];
    const float* w2     = (const float*)d_in[3];
    const float* b2     = (const float*)d_in[4];
    const float* lif_w  = (const float*)d_in[5];
    const float* lif_b  = (const float*)d_in[6];
    const float* fc_w   = (const float*)d_in[7];
    const float* fc_b   = (const float*)d_in[8];
    const float* task_w = (const float*)d_in[9];
    const float* task_b = (const float*)d_in[10];
    const int*   tw     = (const int*)d_in[11];

    int B = in_sizes[0] / 1296;  // x is (B,1,36,36)

    scnn_kernel<<<B, 512, 0, stream>>>(x, w1, b1, w2, b2, lif_w, lif_b,
                                       fc_w, fc_b, task_w, task_b, tw,
                                       (float*)d_out);
}

// Round 7
// 316.941 us; speedup vs baseline: 4.2131x; 4.2131x over previous
//
#include <hip/hip_runtime.h>

#define TH  0.3f
#define DEC 0.2f

// LDS layout (float offsets) — all 16B-aligned where vector-accessed
#define OFF_X    0        // 38*38 = 1444 (x, zero-padded border)
#define OFF_W1   1444     // 10*28 = 280  (repack: [oc][k*9+j], pad to 28)
#define OFF_B1   1724     // 30
#define OFF_W2   1756     // 100*28 = 2800 (repack: [oc][ic][k*9+j], pad 28)
#define OFF_B2   4556     // 30
#define OFF_LIF  4588     // 4
#define OFF_S    4592     // 10*20*20 = 4000 (pooled L1 spikes, padded border); h1 in epilogue
#define OFF_C1X  8592     // 168 overflow L1 cells x 16 floats = 2688 (fp32 state in LDS)
#define SMEM_N   11280    // 45,120 bytes

#define Z4 make_float4(0.f, 0.f, 0.f, 0.f)

__device__ __forceinline__ float spikef(float v) { return v > TH ? 1.f : 0.f; }

// LIF update of one float4 state M (k0..k2 in x,y,z; hh-channel in w), drives D0..D2
#define LIF4(M, D0, D1, D2)                                            \
    {                                                                  \
        float inner_ = fmaf((M).x, lw0, fmaf((M).y, lw1, fmaf((M).z, lw2, lb))); \
        (M).x = ((M).x > TH ? 0.f : (M).x * DEC) + (D0);               \
        (M).y = ((M).y > TH ? 0.f : (M).y * DEC) + (D1);               \
        (M).z = ((M).z > TH ? 0.f : (M).z * DEC) + (D2);               \
        (M).w = ((M).w > TH ? 0.f : (M).w * DEC) + inner_;             \
    }

// stream 27 weights (float4 chunks, immediate consumption), ACC(k,r,c,w)
#define CONV27(WB, ACC)                                                      \
    do {                                                                     \
        float4 w4_;                                                          \
        _Pragma("unroll")                                                    \
        for (int j_ = 0; j_ < 27; ++j_) {                                    \
            if ((j_ & 3) == 0)                                               \
                w4_ = *reinterpret_cast<const float4*>(&sm[(WB) + j_]);      \
            const float wv_ = ((j_ & 3) == 0) ? w4_.x :                      \
                              ((j_ & 3) == 1) ? w4_.y :                      \
                              ((j_ & 3) == 2) ? w4_.z : w4_.w;               \
            const int k_ = j_ / 9, r_ = (j_ - k_ * 9) / 3,                   \
                      c_ = j_ - k_ * 9 - r_ * 3;                             \
            ACC(k_, r_, c_, wv_);                                            \
        }                                                                    \
    } while (0)

#define ACC_L1(K, R, C, W)                                   \
    d[0][K] = fmaf(xv[R][C],         (W), d[0][K]);          \
    d[1][K] = fmaf(xv[R][C + 1],     (W), d[1][K]);          \
    d[2][K] = fmaf(xv[R + 1][C],     (W), d[2][K]);          \
    d[3][K] = fmaf(xv[R + 1][C + 1], (W), d[3][K]);

#define ACC_L2(K, R, C, W)                                   \
    acc[0][K] = fmaf(sv[R][C],         (W), acc[0][K]);      \
    acc[1][K] = fmaf(sv[R][C + 1],     (W), acc[1][K]);      \
    acc[2][K] = fmaf(sv[R + 1][C],     (W), acc[2][K]);      \
    acc[3][K] = fmaf(sv[R + 1][C + 1], (W), acc[3][K]);

// ---- layer 1: one cell (18x18 pooled grid), conv from LDS-x, state by ref ----
__device__ __forceinline__ void l1cell(float* __restrict__ sm, int cell,
                                       float lw0, float lw1, float lw2, float lb,
                                       float4& s0, float4& s1, float4& s2, float4& s3)
{
    int oc  = cell / 324;
    int rem = cell - oc * 324;
    int hh  = rem / 18;
    int ww  = rem - hh * 18;
    int y0 = 2 * hh, x0 = 2 * ww;

    float xv[4][4];
#pragma unroll
    for (int r = 0; r < 4; ++r) {
        float2 a = *reinterpret_cast<const float2*>(&sm[OFF_X + (y0 + r) * 38 + x0]);
        float2 b = *reinterpret_cast<const float2*>(&sm[OFF_X + (y0 + r) * 38 + x0 + 2]);
        xv[r][0] = a.x; xv[r][1] = a.y; xv[r][2] = b.x; xv[r][3] = b.y;
    }
    float d[4][3];
    {
        float b0  = sm[OFF_B1 + oc];
        float b1v = sm[OFF_B1 + 10 + oc];
        float b2v = sm[OFF_B1 + 20 + oc];
#pragma unroll
        for (int p = 0; p < 4; ++p) { d[p][0] = b0; d[p][1] = b1v; d[p][2] = b2v; }
    }
    CONV27(OFF_W1 + oc * 28, ACC_L1);

    float ssum = 0.f;
    LIF4(s0, d[0][0], d[0][1], d[0][2]);
    ssum += spikef(s0.x) + spikef(s0.y) + spikef(s0.z) + spikef(s0.w);
    LIF4(s1, d[1][0], d[1][1], d[1][2]);
    ssum += spikef(s1.x) + spikef(s1.y) + spikef(s1.z) + spikef(s1.w);
    LIF4(s2, d[2][0], d[2][1], d[2][2]);
    ssum += spikef(s2.x) + spikef(s2.y) + spikef(s2.z) + spikef(s2.w);
    LIF4(s3, d[3][0], d[3][1], d[3][2]);
    ssum += spikef(s3.x) + spikef(s3.y) + spikef(s3.z) + spikef(s3.w);

    sm[OFF_S + oc * 400 + (hh + 1) * 20 + (ww + 1)] = ssum * 0.25f;
}

// ---- layer 2: one cell (9x9 grid), conv over S (LDS), state + h1 by ref ----
__device__ __forceinline__ void l2cell(const float* __restrict__ sm, int cell,
                                       float lw0, float lw1, float lw2, float lb,
                                       float4& s0, float4& s1, float4& s2, float4& s3,
                                       float& h0, float& h1, float& h2, float& h3)
{
    int oc  = cell / 81;
    int rem = cell - oc * 81;
    int hh  = rem / 9;
    int ww  = rem - hh * 9;
    int y0 = 2 * hh, x0 = 2 * ww;

    float acc[4][3];
    {
        float b20 = 4.f * sm[OFF_B2 + oc];
        float b21 = 4.f * sm[OFF_B2 + 10 + oc];
        float b22 = 4.f * sm[OFF_B2 + 20 + oc];
#pragma unroll
        for (int p = 0; p < 4; ++p) { acc[p][0] = b20; acc[p][1] = b21; acc[p][2] = b22; }
    }

    const int sb = OFF_S + y0 * 20 + x0;      // even -> float2 aligned
    const int wb = OFF_W2 + (oc * 10) * 28;   // 16B aligned

    for (int ic = 0; ic < 10; ++ic) {
        float sv[4][4];
#pragma unroll
        for (int r = 0; r < 4; ++r) {
            float2 a = *reinterpret_cast<const float2*>(&sm[sb + ic * 400 + r * 20]);
            float2 b = *reinterpret_cast<const float2*>(&sm[sb + ic * 400 + r * 20 + 2]);
            sv[r][0] = a.x; sv[r][1] = a.y; sv[r][2] = b.x; sv[r][3] = b.y;
        }
        CONV27(wb + ic * 28, ACC_L2);
    }

    LIF4(s0, acc[0][0], acc[0][1], acc[0][2]);
    h0 += spikef(s0.x) * 0.25f; h1 += spikef(s0.y) * 0.25f;
    h2 += spikef(s0.z) * 0.25f; h3 += spikef(s0.w) * 0.25f;
    LIF4(s1, acc[1][0], acc[1][1], acc[1][2]);
    h0 += spikef(s1.x) * 0.25f; h1 += spikef(s1.y) * 0.25f;
    h2 += spikef(s1.z) * 0.25f; h3 += spikef(s1.w) * 0.25f;
    LIF4(s2, acc[2][0], acc[2][1], acc[2][2]);
    h0 += spikef(s2.x) * 0.25f; h1 += spikef(s2.y) * 0.25f;
    h2 += spikef(s2.z) * 0.25f; h3 += spikef(s2.w) * 0.25f;
    LIF4(s3, acc[3][0], acc[3][1], acc[3][2]);
    h0 += spikef(s3.x) * 0.25f; h1 += spikef(s3.y) * 0.25f;
    h2 += spikef(s3.z) * 0.25f; h3 += spikef(s3.w) * 0.25f;
}

__global__ __launch_bounds__(1024)
void scnn_kernel(const float* __restrict__ x,
                 const float* __restrict__ w1, const float* __restrict__ b1,
                 const float* __restrict__ w2, const float* __restrict__ b2,
                 const float* __restrict__ lif_w, const float* __restrict__ lif_b,
                 const float* __restrict__ fc_w, const float* __restrict__ fc_b,
                 const float* __restrict__ task_w, const float* __restrict__ task_b,
                 const int* __restrict__ tw_ptr,
                 float* __restrict__ out)
{
    __shared__ float sm[SMEM_N];
    const int tid = threadIdx.x;
    const int b   = blockIdx.x;
    const int T   = tw_ptr[0];

    for (int i = tid; i < SMEM_N; i += 1024) sm[i] = 0.f;
    __syncthreads();

    for (int i = tid; i < 1296; i += 1024) {
        int h = i / 36, w = i - h * 36;
        sm[OFF_X + (h + 1) * 38 + (w + 1)] = x[b * 1296 + i];
    }
    if (tid < 270) { // w1 (3,10,1,3,3) -> [oc][k*9+j] pad 28
        int k = tid / 90, r = tid - k * 90;
        int oc = r / 9, j = r - oc * 9;
        sm[OFF_W1 + oc * 28 + k * 9 + j] = w1[tid];
    }
    if (tid < 30)  sm[OFF_B1 + tid] = b1[tid];
    for (int i = tid; i < 2700; i += 1024) { // w2 (3,10,10,3,3) -> [oc][ic][k*9+j] pad 28
        int k = i / 900, r1 = i - k * 900;
        int oc = r1 / 90, r2 = r1 - oc * 90;
        int ic = r2 / 9,  j  = r2 - ic * 9;
        sm[OFF_W2 + (oc * 10 + ic) * 28 + k * 9 + j] = w2[i];
    }
    if (tid < 30)  sm[OFF_B2 + tid] = b2[tid];
    if (tid < 3)   sm[OFF_LIF + tid] = lif_w[tid];
    if (tid == 0)  sm[OFF_LIF + 3] = lif_b[0];
    __syncthreads();

    const float lw0 = sm[OFF_LIF + 0], lw1 = sm[OFF_LIF + 1],
                lw2 = sm[OFF_LIF + 2], lb  = sm[OFF_LIF + 3];

    // persistent state: 3 L1 cells (48 f) + 1 L2 cell (16 f) + h1 (4 f) = 68 floats
    float4 mA0=Z4,mA1=Z4,mA2=Z4,mA3=Z4;   // L1 cell tid
    float4 mB0=Z4,mB1=Z4,mB2=Z4,mB3=Z4;   // L1 cell tid+1024
    float4 mC0=Z4,mC1=Z4,mC2=Z4,mC3=Z4;   // L1 cell tid+2048
    float4 mP0=Z4,mP1=Z4,mP2=Z4,mP3=Z4;   // L2 cell tid (tid<810)
    float hA0=0.f,hA1=0.f,hA2=0.f,hA3=0.f;

    for (int t = 0; t < T; ++t) {
        l1cell(sm, tid,        lw0, lw1, lw2, lb, mA0, mA1, mA2, mA3);
        l1cell(sm, tid + 1024, lw0, lw1, lw2, lb, mB0, mB1, mB2, mB3);
        l1cell(sm, tid + 2048, lw0, lw1, lw2, lb, mC0, mC1, mC2, mC3);
        if (tid < 3240 - 3072) {   // 168 overflow cells: state lives in LDS (fp32)
            float4* cp = reinterpret_cast<float4*>(&sm[OFF_C1X + tid * 16]);
            float4 s0 = cp[0], s1 = cp[1], s2 = cp[2], s3 = cp[3];
            l1cell(sm, tid + 3072, lw0, lw1, lw2, lb, s0, s1, s2, s3);
            cp[0] = s0; cp[1] = s1; cp[2] = s2; cp[3] = s3;
        }
        __syncthreads();

        if (tid < 810)
            l2cell(sm, tid, lw0, lw1, lw2, lb, mP0, mP1, mP2, mP3, hA0, hA1, hA2, hA3);
        __syncthreads();
    }

    // ---- epilogue: h1 -> LDS (overwrites S), FC(50x3240), task heads ----
    if (tid < 810)
        *reinterpret_cast<float4*>(&sm[OFF_S + tid * 4]) = make_float4(hA0, hA1, hA2, hA3);
    __syncthreads();

    float invT = 1.f / (float)T;
    int f = tid >> 4, g = tid & 15;
    if (f < 50) {
        const float* wrow = fc_w + f * 3240;
        float p0 = 0.f, p1 = 0.f;
        for (int j = g; j + 16 < 3240; j += 32) {
            p0 = fmaf(sm[OFF_S + j], wrow[j], p0);
            p1 = fmaf(sm[OFF_S + j + 16], wrow[j + 16], p1);
        }
        { int j = 3232 + g; if (j < 3240) p0 = fmaf(sm[OFF_S + j], wrow[j], p0); }
        float p = p0 + p1;
        p += __shfl_xor(p, 1);
        p += __shfl_xor(p, 2);
        p += __shfl_xor(p, 4);
        p += __shfl_xor(p, 8);
        if (g == 0) sm[OFF_X + f] = p * invT + fc_b[f];
    }
    __syncthreads();

    if (tid < 30) {
        float acc = task_b[tid];
        const float* twp = task_w + tid * 50;
        for (int j = 0; j < 50; ++j) acc = fmaf(sm[OFF_X + j], twp[j], acc);
        out[b * 30 + tid] = acc;
    }
}

extern "C" void kernel_launch(void* const* d_in, const int* in_sizes, int n_in,
                              void* d_out, int out_size, void* d_ws, size_t ws_size,
                              hipStream_t stream) {
    const float* x      = (const float*)d_in[0];
    const float* w1     = (const float*)d_in[1];
    const float* b1     = (const float*)d_in[2];
    const float* w2     = (const float*)d_in[3];
    const float* b2     = (const float*)d_in[4];
    const float* lif_w  = (const float*)d_in[5];
    const float* lif_b  = (const float*)d_in[6];
    const float* fc_w   = (const float*)d_in[7];
    const float* fc_b   = (const float*)d_in[8];
    const float* task_w = (const float*)d_in[9];
    const float* task_b = (const float*)d_in[10];
    const int*   tw     = (const int*)d_in[11];

    int B = in_sizes[0] / 1296;  // x is (B,1,36,36)

    scnn_kernel<<<B, 1024, 0, stream>>>(x, w1, b1, w2, b2, lif_w, lif_b,
                                        fc_w, fc_b, task_w, task_b, tw,
                                        (float*)d_out);
}

// Round 8
// 299.219 us; speedup vs baseline: 4.4626x; 1.0592x over previous
//
#include <hip/hip_runtime.h>

#define TH  0.3f
#define DEC 0.2f

// LDS layout (float offsets) — all 16B-aligned where vector-accessed
#define OFF_X    0        // 38*38 = 1444 (x, zero-padded border)
#define OFF_W1   1444     // 10*28 = 280  (repack: [oc][k*9+j], pad to 28)
#define OFF_B1   1724     // 30
#define OFF_W2   1756     // 100*28 = 2800 (repack: [oc][ic][k*9+j], pad 28)
#define OFF_B2   4556     // 30
#define OFF_LIF  4588     // 4
#define OFF_S    4592     // 10*20*20 = 4000 (pooled L1 spikes, padded border); h1 in epilogue
#define OFF_C1X  8592     // 168 overflow L1 cells x 17-float stride (odd stride: bank-conflict-free)
#define SMEM_N   11448    // 45,792 bytes

#define Z4 make_float4(0.f, 0.f, 0.f, 0.f)

__device__ __forceinline__ float spikef(float v) { return v > TH ? 1.f : 0.f; }

// LIF update of one float4 state M (k0..k2 in x,y,z; hh-channel in w), drives D0..D2
#define LIF4(M, D0, D1, D2)                                            \
    {                                                                  \
        float inner_ = fmaf((M).x, lw0, fmaf((M).y, lw1, fmaf((M).z, lw2, lb))); \
        (M).x = ((M).x > TH ? 0.f : (M).x * DEC) + (D0);               \
        (M).y = ((M).y > TH ? 0.f : (M).y * DEC) + (D1);               \
        (M).z = ((M).z > TH ? 0.f : (M).z * DEC) + (D2);               \
        (M).w = ((M).w > TH ? 0.f : (M).w * DEC) + inner_;             \
    }

// stream 27 weights (float4 chunks, immediate consumption), ACC(k,r,c,w)
#define CONV27(WB, ACC)                                                      \
    do {                                                                     \
        float4 w4_;                                                          \
        _Pragma("unroll")                                                    \
        for (int j_ = 0; j_ < 27; ++j_) {                                    \
            if ((j_ & 3) == 0)                                               \
                w4_ = *reinterpret_cast<const float4*>(&sm[(WB) + j_]);      \
            const float wv_ = ((j_ & 3) == 0) ? w4_.x :                      \
                              ((j_ & 3) == 1) ? w4_.y :                      \
                              ((j_ & 3) == 2) ? w4_.z : w4_.w;               \
            const int k_ = j_ / 9, r_ = (j_ - k_ * 9) / 3,                   \
                      c_ = j_ - k_ * 9 - r_ * 3;                             \
            ACC(k_, r_, c_, wv_);                                            \
        }                                                                    \
    } while (0)

#define ACC_L1(K, R, C, W)                                   \
    d[0][K] = fmaf(xv[R][C],         (W), d[0][K]);          \
    d[1][K] = fmaf(xv[R][C + 1],     (W), d[1][K]);          \
    d[2][K] = fmaf(xv[R + 1][C],     (W), d[2][K]);          \
    d[3][K] = fmaf(xv[R + 1][C + 1], (W), d[3][K]);

#define ACC_L2(K, R, C, W)                                   \
    acc[0][K] = fmaf(sv[R][C],         (W), acc[0][K]);      \
    acc[1][K] = fmaf(sv[R][C + 1],     (W), acc[1][K]);      \
    acc[2][K] = fmaf(sv[R + 1][C],     (W), acc[2][K]);      \
    acc[3][K] = fmaf(sv[R + 1][C + 1], (W), acc[3][K]);

// ---- layer 1: one cell (18x18 pooled grid), conv from LDS-x, state by ref ----
__device__ __forceinline__ void l1cell(float* __restrict__ sm, int cell,
                                       float lw0, float lw1, float lw2, float lb,
                                       float4& s0, float4& s1, float4& s2, float4& s3)
{
    int oc  = cell / 324;
    int rem = cell - oc * 324;
    int hh  = rem / 18;
    int ww  = rem - hh * 18;
    int y0 = 2 * hh, x0 = 2 * ww;

    float xv[4][4];
#pragma unroll
    for (int r = 0; r < 4; ++r) {
        float2 a = *reinterpret_cast<const float2*>(&sm[OFF_X + (y0 + r) * 38 + x0]);
        float2 b = *reinterpret_cast<const float2*>(&sm[OFF_X + (y0 + r) * 38 + x0 + 2]);
        xv[r][0] = a.x; xv[r][1] = a.y; xv[r][2] = b.x; xv[r][3] = b.y;
    }
    float d[4][3];
    {
        float b0  = sm[OFF_B1 + oc];
        float b1v = sm[OFF_B1 + 10 + oc];
        float b2v = sm[OFF_B1 + 20 + oc];
#pragma unroll
        for (int p = 0; p < 4; ++p) { d[p][0] = b0; d[p][1] = b1v; d[p][2] = b2v; }
    }
    CONV27(OFF_W1 + oc * 28, ACC_L1);

    float ssum = 0.f;
    LIF4(s0, d[0][0], d[0][1], d[0][2]);
    ssum += spikef(s0.x) + spikef(s0.y) + spikef(s0.z) + spikef(s0.w);
    LIF4(s1, d[1][0], d[1][1], d[1][2]);
    ssum += spikef(s1.x) + spikef(s1.y) + spikef(s1.z) + spikef(s1.w);
    LIF4(s2, d[2][0], d[2][1], d[2][2]);
    ssum += spikef(s2.x) + spikef(s2.y) + spikef(s2.z) + spikef(s2.w);
    LIF4(s3, d[3][0], d[3][1], d[3][2]);
    ssum += spikef(s3.x) + spikef(s3.y) + spikef(s3.z) + spikef(s3.w);

    sm[OFF_S + oc * 400 + (hh + 1) * 20 + (ww + 1)] = ssum * 0.25f;
}

// ---- layer 2: one cell (9x9 grid), conv over S (LDS), state + h1 by ref ----
__device__ __forceinline__ void l2cell(const float* __restrict__ sm, int cell,
                                       float lw0, float lw1, float lw2, float lb,
                                       float4& s0, float4& s1, float4& s2, float4& s3,
                                       float& h0, float& h1, float& h2, float& h3)
{
    int oc  = cell / 81;
    int rem = cell - oc * 81;
    int hh  = rem / 9;
    int ww  = rem - hh * 9;
    int y0 = 2 * hh, x0 = 2 * ww;

    float acc[4][3];
    {
        float b20 = 4.f * sm[OFF_B2 + oc];
        float b21 = 4.f * sm[OFF_B2 + 10 + oc];
        float b22 = 4.f * sm[OFF_B2 + 20 + oc];
#pragma unroll
        for (int p = 0; p < 4; ++p) { acc[p][0] = b20; acc[p][1] = b21; acc[p][2] = b22; }
    }

    const int sb = OFF_S + y0 * 20 + x0;      // even -> float2 aligned
    const int wb = OFF_W2 + (oc * 10) * 28;   // 16B aligned

    for (int ic = 0; ic < 10; ++ic) {
        float sv[4][4];
#pragma unroll
        for (int r = 0; r < 4; ++r) {
            float2 a = *reinterpret_cast<const float2*>(&sm[sb + ic * 400 + r * 20]);
            float2 b = *reinterpret_cast<const float2*>(&sm[sb + ic * 400 + r * 20 + 2]);
            sv[r][0] = a.x; sv[r][1] = a.y; sv[r][2] = b.x; sv[r][3] = b.y;
        }
        CONV27(wb + ic * 28, ACC_L2);
    }

    LIF4(s0, acc[0][0], acc[0][1], acc[0][2]);
    h0 += spikef(s0.x) * 0.25f; h1 += spikef(s0.y) * 0.25f;
    h2 += spikef(s0.z) * 0.25f; h3 += spikef(s0.w) * 0.25f;
    LIF4(s1, acc[1][0], acc[1][1], acc[1][2]);
    h0 += spikef(s1.x) * 0.25f; h1 += spikef(s1.y) * 0.25f;
    h2 += spikef(s1.z) * 0.25f; h3 += spikef(s1.w) * 0.25f;
    LIF4(s2, acc[2][0], acc[2][1], acc[2][2]);
    h0 += spikef(s2.x) * 0.25f; h1 += spikef(s2.y) * 0.25f;
    h2 += spikef(s2.z) * 0.25f; h3 += spikef(s2.w) * 0.25f;
    LIF4(s3, acc[3][0], acc[3][1], acc[3][2]);
    h0 += spikef(s3.x) * 0.25f; h1 += spikef(s3.y) * 0.25f;
    h2 += spikef(s3.z) * 0.25f; h3 += spikef(s3.w) * 0.25f;
}

__attribute__((amdgpu_waves_per_eu(4, 4)))
__global__ __launch_bounds__(1024, 4)
void scnn_kernel(const float* __restrict__ x,
                 const float* __restrict__ w1, const float* __restrict__ b1,
                 const float* __restrict__ w2, const float* __restrict__ b2,
                 const float* __restrict__ lif_w, const float* __restrict__ lif_b,
                 const float* __restrict__ fc_w, const float* __restrict__ fc_b,
                 const float* __restrict__ task_w, const float* __restrict__ task_b,
                 const int* __restrict__ tw_ptr,
                 float* __restrict__ out)
{
    __shared__ float sm[SMEM_N];
    const int tid = threadIdx.x;
    const int b   = blockIdx.x;
    const int T   = tw_ptr[0];

    for (int i = tid; i < SMEM_N; i += 1024) sm[i] = 0.f;
    __syncthreads();

    for (int i = tid; i < 1296; i += 1024) {
        int h = i / 36, w = i - h * 36;
        sm[OFF_X + (h + 1) * 38 + (w + 1)] = x[b * 1296 + i];
    }
    if (tid < 270) { // w1 (3,10,1,3,3) -> [oc][k*9+j] pad 28
        int k = tid / 90, r = tid - k * 90;
        int oc = r / 9, j = r - oc * 9;
        sm[OFF_W1 + oc * 28 + k * 9 + j] = w1[tid];
    }
    if (tid < 30)  sm[OFF_B1 + tid] = b1[tid];
    for (int i = tid; i < 2700; i += 1024) { // w2 (3,10,10,3,3) -> [oc][ic][k*9+j] pad 28
        int k = i / 900, r1 = i - k * 900;
        int oc = r1 / 90, r2 = r1 - oc * 90;
        int ic = r2 / 9,  j  = r2 - ic * 9;
        sm[OFF_W2 + (oc * 10 + ic) * 28 + k * 9 + j] = w2[i];
    }
    if (tid < 30)  sm[OFF_B2 + tid] = b2[tid];
    if (tid < 3)   sm[OFF_LIF + tid] = lif_w[tid];
    if (tid == 0)  sm[OFF_LIF + 3] = lif_b[0];
    __syncthreads();

    const float lw0 = sm[OFF_LIF + 0], lw1 = sm[OFF_LIF + 1],
                lw2 = sm[OFF_LIF + 2], lb  = sm[OFF_LIF + 3];

    // persistent state: 3 L1 cells (48 f) + 1 L2 cell (16 f) + h1 (4 f) = 68 floats
    float4 mA0=Z4,mA1=Z4,mA2=Z4,mA3=Z4;   // L1 cell tid
    float4 mB0=Z4,mB1=Z4,mB2=Z4,mB3=Z4;   // L1 cell tid+1024
    float4 mC0=Z4,mC1=Z4,mC2=Z4,mC3=Z4;   // L1 cell tid+2048
    float4 mP0=Z4,mP1=Z4,mP2=Z4,mP3=Z4;   // L2 cell tid (tid<810)
    float hA0=0.f,hA1=0.f,hA2=0.f,hA3=0.f;

    for (int t = 0; t < T; ++t) {
        l1cell(sm, tid,        lw0, lw1, lw2, lb, mA0, mA1, mA2, mA3);
        l1cell(sm, tid + 1024, lw0, lw1, lw2, lb, mB0, mB1, mB2, mB3);
        l1cell(sm, tid + 2048, lw0, lw1, lw2, lb, mC0, mC1, mC2, mC3);
        if (tid < 3240 - 3072) {   // 168 overflow cells: LDS state, odd-stride (no conflicts)
            float* cp = &sm[OFF_C1X + tid * 17];
            float4 s0 = make_float4(cp[0],  cp[1],  cp[2],  cp[3]);
            float4 s1 = make_float4(cp[4],  cp[5],  cp[6],  cp[7]);
            float4 s2 = make_float4(cp[8],  cp[9],  cp[10], cp[11]);
            float4 s3 = make_float4(cp[12], cp[13], cp[14], cp[15]);
            l1cell(sm, tid + 3072, lw0, lw1, lw2, lb, s0, s1, s2, s3);
            cp[0]=s0.x;  cp[1]=s0.y;  cp[2]=s0.z;  cp[3]=s0.w;
            cp[4]=s1.x;  cp[5]=s1.y;  cp[6]=s1.z;  cp[7]=s1.w;
            cp[8]=s2.x;  cp[9]=s2.y;  cp[10]=s2.z; cp[11]=s2.w;
            cp[12]=s3.x; cp[13]=s3.y; cp[14]=s3.z; cp[15]=s3.w;
        }
        __syncthreads();

        if (tid < 810)
            l2cell(sm, tid, lw0, lw1, lw2, lb, mP0, mP1, mP2, mP3, hA0, hA1, hA2, hA3);
        __syncthreads();
    }

    // ---- epilogue: h1 -> LDS (overwrites S), FC(50x3240), task heads ----
    if (tid < 810)
        *reinterpret_cast<float4*>(&sm[OFF_S + tid * 4]) = make_float4(hA0, hA1, hA2, hA3);
    __syncthreads();

    float invT = 1.f / (float)T;
    int f = tid >> 4, g = tid & 15;
    if (f < 50) {
        const float* wrow = fc_w + f * 3240;
        float p0 = 0.f, p1 = 0.f;
        for (int j = g; j + 16 < 3240; j += 32) {
            p0 = fmaf(sm[OFF_S + j], wrow[j], p0);
            p1 = fmaf(sm[OFF_S + j + 16], wrow[j + 16], p1);
        }
        { int j = 3232 + g; if (j < 3240) p0 = fmaf(sm[OFF_S + j], wrow[j], p0); }
        float p = p0 + p1;
        p += __shfl_xor(p, 1);
        p += __shfl_xor(p, 2);
        p += __shfl_xor(p, 4);
        p += __shfl_xor(p, 8);
        if (g == 0) sm[OFF_X + f] = p * invT + fc_b[f];
    }
    __syncthreads();

    if (tid < 30) {
        float acc = task_b[tid];
        const float* twp = task_w + tid * 50;
        for (int j = 0; j < 50; ++j) acc = fmaf(sm[OFF_X + j], twp[j], acc);
        out[b * 30 + tid] = acc;
    }
}

extern "C" void kernel_launch(void* const* d_in, const int* in_sizes, int n_in,
                              void* d_out, int out_size, void* d_ws, size_t ws_size,
                              hipStream_t stream) {
    const float* x      = (const float*)d_in[0];
    const float* w1     = (const float*)d_in[1];
    const float* b1     = (const float*)d_in[2];
    const float* w2     = (const float*)d_in[3];
    const float* b2     = (const float*)d_in[4];
    const float* lif_w  = (const float*)d_in[5];
    const float* lif_b  = (const float*)d_in[6];
    const float* fc_w   = (const float*)d_in[7];
    const float* fc_b   = (const float*)d_in[8];
    const float* task_w = (const float*)d_in[9];
    const float* task_b = (const float*)d_in[10];
    const int*   tw     = (const int*)d_in[11];

    int B = in_sizes[0] / 1296;  // x is (B,1,36,36)

    scnn_kernel<<<B, 1024, 0, stream>>>(x, w1, b1, w2, b2, lif_w, lif_b,
                                        fc_w, fc_b, task_w, task_b, tw,
                                        (float*)d_out);
}

// Round 9
// 249.492 us; speedup vs baseline: 5.3521x; 1.1993x over previous
//
#include <hip/hip_runtime.h>

#define TH  0.3f
#define DEC 0.2f

// LDS layout (float offsets) — all 16B-aligned where vector-accessed
#define OFF_X    0        // 38*38 = 1444 (x, zero-padded border)
#define OFF_W1   1444     // 10*28 = 280  (repack: [oc][k*9+j], pad to 28)
#define OFF_B1   1724     // 30
#define OFF_W2   1756     // 100*28 = 2800 (repack: [oc][ic][k*9+j], pad 28)
#define OFF_B2   4556     // 30
#define OFF_LIF  4588     // 4
#define OFF_S    4592     // 10*20*20 = 4000 (pooled L1 spikes, padded border); h1 in epilogue
#define OFF_C1X  8592     // 168 overflow L1 cells x 17-float stride (bank-conflict-free)
#define SMEM_N   11448    // 45,792 bytes

#define Z4 make_float4(0.f, 0.f, 0.f, 0.f)

__device__ __forceinline__ float spikef(float v) { return v > TH ? 1.f : 0.f; }

// ---- AGPR residency: values defined by "=a" and consumed by "a" get AGPR
// register class, so they LIVE in the (otherwise unused) accum half of the
// unified register file. Non-volatile asm: scheduler may interleave freely.
__device__ __forceinline__ float ag_w(float v) {
    float a;
    asm("v_accvgpr_write_b32 %0, %1" : "=a"(a) : "v"(v));
    return a;
}
__device__ __forceinline__ float ag_r(float a) {
    float v;
    asm("v_accvgpr_read_b32 %0, %1" : "=v"(v) : "a"(a));
    return v;
}

#define AG16_DECL(P) \
    float P##0=ag_w(0.f), P##1=ag_w(0.f), P##2=ag_w(0.f), P##3=ag_w(0.f),   \
          P##4=ag_w(0.f), P##5=ag_w(0.f), P##6=ag_w(0.f), P##7=ag_w(0.f),   \
          P##8=ag_w(0.f), P##9=ag_w(0.f), P##10=ag_w(0.f), P##11=ag_w(0.f), \
          P##12=ag_w(0.f), P##13=ag_w(0.f), P##14=ag_w(0.f), P##15=ag_w(0.f)

#define AG16_LOAD(P, S0, S1, S2, S3) \
    float4 S0 = make_float4(ag_r(P##0),  ag_r(P##1),  ag_r(P##2),  ag_r(P##3));  \
    float4 S1 = make_float4(ag_r(P##4),  ag_r(P##5),  ag_r(P##6),  ag_r(P##7));  \
    float4 S2 = make_float4(ag_r(P##8),  ag_r(P##9),  ag_r(P##10), ag_r(P##11)); \
    float4 S3 = make_float4(ag_r(P##12), ag_r(P##13), ag_r(P##14), ag_r(P##15))

#define AG16_STORE(P, S0, S1, S2, S3) \
    P##0=ag_w(S0.x);  P##1=ag_w(S0.y);  P##2=ag_w(S0.z);  P##3=ag_w(S0.w);  \
    P##4=ag_w(S1.x);  P##5=ag_w(S1.y);  P##6=ag_w(S1.z);  P##7=ag_w(S1.w);  \
    P##8=ag_w(S2.x);  P##9=ag_w(S2.y);  P##10=ag_w(S2.z); P##11=ag_w(S2.w); \
    P##12=ag_w(S3.x); P##13=ag_w(S3.y); P##14=ag_w(S3.z); P##15=ag_w(S3.w)

// LIF update of one float4 state M (k0..k2 in x,y,z; hh-channel in w), drives D0..D2
#define LIF4(M, D0, D1, D2)                                            \
    {                                                                  \
        float inner_ = fmaf((M).x, lw0, fmaf((M).y, lw1, fmaf((M).z, lw2, lb))); \
        (M).x = ((M).x > TH ? 0.f : (M).x * DEC) + (D0);               \
        (M).y = ((M).y > TH ? 0.f : (M).y * DEC) + (D1);               \
        (M).z = ((M).z > TH ? 0.f : (M).z * DEC) + (D2);               \
        (M).w = ((M).w > TH ? 0.f : (M).w * DEC) + inner_;             \
    }

// stream 27 weights (float4 chunks, immediate consumption), ACC(k,r,c,w)
#define CONV27(WB, ACC)                                                      \
    do {                                                                     \
        float4 w4_;                                                          \
        _Pragma("unroll")                                                    \
        for (int j_ = 0; j_ < 27; ++j_) {                                    \
            if ((j_ & 3) == 0)                                               \
                w4_ = *reinterpret_cast<const float4*>(&sm[(WB) + j_]);      \
            const float wv_ = ((j_ & 3) == 0) ? w4_.x :                      \
                              ((j_ & 3) == 1) ? w4_.y :                      \
                              ((j_ & 3) == 2) ? w4_.z : w4_.w;               \
            const int k_ = j_ / 9, r_ = (j_ - k_ * 9) / 3,                   \
                      c_ = j_ - k_ * 9 - r_ * 3;                             \
            ACC(k_, r_, c_, wv_);                                            \
        }                                                                    \
    } while (0)

#define ACC_L1(K, R, C, W)                                   \
    d[0][K] = fmaf(xv[R][C],         (W), d[0][K]);          \
    d[1][K] = fmaf(xv[R][C + 1],     (W), d[1][K]);          \
    d[2][K] = fmaf(xv[R + 1][C],     (W), d[2][K]);          \
    d[3][K] = fmaf(xv[R + 1][C + 1], (W), d[3][K]);

#define ACC_L2(K, R, C, W)                                   \
    acc[0][K] = fmaf(sv[R][C],         (W), acc[0][K]);      \
    acc[1][K] = fmaf(sv[R][C + 1],     (W), acc[1][K]);      \
    acc[2][K] = fmaf(sv[R + 1][C],     (W), acc[2][K]);      \
    acc[3][K] = fmaf(sv[R + 1][C + 1], (W), acc[3][K]);

// ---- layer 1: one cell (18x18 pooled grid), conv from LDS-x, state by ref ----
__device__ __forceinline__ void l1cell(float* __restrict__ sm, int cell,
                                       float lw0, float lw1, float lw2, float lb,
                                       float4& s0, float4& s1, float4& s2, float4& s3)
{
    int oc  = cell / 324;
    int rem = cell - oc * 324;
    int hh  = rem / 18;
    int ww  = rem - hh * 18;
    int y0 = 2 * hh, x0 = 2 * ww;

    float xv[4][4];
#pragma unroll
    for (int r = 0; r < 4; ++r) {
        float2 a = *reinterpret_cast<const float2*>(&sm[OFF_X + (y0 + r) * 38 + x0]);
        float2 b = *reinterpret_cast<const float2*>(&sm[OFF_X + (y0 + r) * 38 + x0 + 2]);
        xv[r][0] = a.x; xv[r][1] = a.y; xv[r][2] = b.x; xv[r][3] = b.y;
    }
    float d[4][3];
    {
        float b0  = sm[OFF_B1 + oc];
        float b1v = sm[OFF_B1 + 10 + oc];
        float b2v = sm[OFF_B1 + 20 + oc];
#pragma unroll
        for (int p = 0; p < 4; ++p) { d[p][0] = b0; d[p][1] = b1v; d[p][2] = b2v; }
    }
    CONV27(OFF_W1 + oc * 28, ACC_L1);

    float ssum = 0.f;
    LIF4(s0, d[0][0], d[0][1], d[0][2]);
    ssum += spikef(s0.x) + spikef(s0.y) + spikef(s0.z) + spikef(s0.w);
    LIF4(s1, d[1][0], d[1][1], d[1][2]);
    ssum += spikef(s1.x) + spikef(s1.y) + spikef(s1.z) + spikef(s1.w);
    LIF4(s2, d[2][0], d[2][1], d[2][2]);
    ssum += spikef(s2.x) + spikef(s2.y) + spikef(s2.z) + spikef(s2.w);
    LIF4(s3, d[3][0], d[3][1], d[3][2]);
    ssum += spikef(s3.x) + spikef(s3.y) + spikef(s3.z) + spikef(s3.w);

    sm[OFF_S + oc * 400 + (hh + 1) * 20 + (ww + 1)] = ssum * 0.25f;
}

// ---- layer 2: one cell (9x9 grid), conv over S (LDS), state + h1 by ref ----
__device__ __forceinline__ void l2cell(const float* __restrict__ sm, int cell,
                                       float lw0, float lw1, float lw2, float lb,
                                       float4& s0, float4& s1, float4& s2, float4& s3,
                                       float& h0, float& h1, float& h2, float& h3)
{
    int oc  = cell / 81;
    int rem = cell - oc * 81;
    int hh  = rem / 9;
    int ww  = rem - hh * 9;
    int y0 = 2 * hh, x0 = 2 * ww;

    float acc[4][3];
    {
        float b20 = 4.f * sm[OFF_B2 + oc];
        float b21 = 4.f * sm[OFF_B2 + 10 + oc];
        float b22 = 4.f * sm[OFF_B2 + 20 + oc];
#pragma unroll
        for (int p = 0; p < 4; ++p) { acc[p][0] = b20; acc[p][1] = b21; acc[p][2] = b22; }
    }

    const int sb = OFF_S + y0 * 20 + x0;      // even -> float2 aligned
    const int wb = OFF_W2 + (oc * 10) * 28;   // 16B aligned

    for (int ic = 0; ic < 10; ++ic) {
        float sv[4][4];
#pragma unroll
        for (int r = 0; r < 4; ++r) {
            float2 a = *reinterpret_cast<const float2*>(&sm[sb + ic * 400 + r * 20]);
            float2 b = *reinterpret_cast<const float2*>(&sm[sb + ic * 400 + r * 20 + 2]);
            sv[r][0] = a.x; sv[r][1] = a.y; sv[r][2] = b.x; sv[r][3] = b.y;
        }
        CONV27(wb + ic * 28, ACC_L2);
    }

    LIF4(s0, acc[0][0], acc[0][1], acc[0][2]);
    h0 += spikef(s0.x) * 0.25f; h1 += spikef(s0.y) * 0.25f;
    h2 += spikef(s0.z) * 0.25f; h3 += spikef(s0.w) * 0.25f;
    LIF4(s1, acc[1][0], acc[1][1], acc[1][2]);
    h0 += spikef(s1.x) * 0.25f; h1 += spikef(s1.y) * 0.25f;
    h2 += spikef(s1.z) * 0.25f; h3 += spikef(s1.w) * 0.25f;
    LIF4(s2, acc[2][0], acc[2][1], acc[2][2]);
    h0 += spikef(s2.x) * 0.25f; h1 += spikef(s2.y) * 0.25f;
    h2 += spikef(s2.z) * 0.25f; h3 += spikef(s2.w) * 0.25f;
    LIF4(s3, acc[3][0], acc[3][1], acc[3][2]);
    h0 += spikef(s3.x) * 0.25f; h1 += spikef(s3.y) * 0.25f;
    h2 += spikef(s3.z) * 0.25f; h3 += spikef(s3.w) * 0.25f;
}

__attribute__((amdgpu_waves_per_eu(4, 4)))
__global__ __launch_bounds__(1024)
void scnn_kernel(const float* __restrict__ x,
                 const float* __restrict__ w1, const float* __restrict__ b1,
                 const float* __restrict__ w2, const float* __restrict__ b2,
                 const float* __restrict__ lif_w, const float* __restrict__ lif_b,
                 const float* __restrict__ fc_w, const float* __restrict__ fc_b,
                 const float* __restrict__ task_w, const float* __restrict__ task_b,
                 const int* __restrict__ tw_ptr,
                 float* __restrict__ out)
{
    __shared__ float sm[SMEM_N];
    const int tid = threadIdx.x;
    const int b   = blockIdx.x;
    const int T   = tw_ptr[0];

    for (int i = tid; i < SMEM_N; i += 1024) sm[i] = 0.f;
    __syncthreads();

    for (int i = tid; i < 1296; i += 1024) {
        int h = i / 36, w = i - h * 36;
        sm[OFF_X + (h + 1) * 38 + (w + 1)] = x[b * 1296 + i];
    }
    if (tid < 270) { // w1 (3,10,1,3,3) -> [oc][k*9+j] pad 28
        int k = tid / 90, r = tid - k * 90;
        int oc = r / 9, j = r - oc * 9;
        sm[OFF_W1 + oc * 28 + k * 9 + j] = w1[tid];
    }
    if (tid < 30)  sm[OFF_B1 + tid] = b1[tid];
    for (int i = tid; i < 2700; i += 1024) { // w2 (3,10,10,3,3) -> [oc][ic][k*9+j] pad 28
        int k = i / 900, r1 = i - k * 900;
        int oc = r1 / 90, r2 = r1 - oc * 90;
        int ic = r2 / 9,  j  = r2 - ic * 9;
        sm[OFF_W2 + (oc * 10 + ic) * 28 + k * 9 + j] = w2[i];
    }
    if (tid < 30)  sm[OFF_B2 + tid] = b2[tid];
    if (tid < 3)   sm[OFF_LIF + tid] = lif_w[tid];
    if (tid == 0)  sm[OFF_LIF + 3] = lif_b[0];
    __syncthreads();

    const float lw0 = sm[OFF_LIF + 0], lw1 = sm[OFF_LIF + 1],
                lw2 = sm[OFF_LIF + 2], lb  = sm[OFF_LIF + 3];

    // persistent state: 64 floats/thread pinned in AGPRs (the unused accum half)
    AG16_DECL(aA);   // L1 cell tid
    AG16_DECL(aB);   // L1 cell tid+1024
    AG16_DECL(aC);   // L1 cell tid+2048
    AG16_DECL(aP);   // L2 cell tid (tid<810)
    float hA0=0.f,hA1=0.f,hA2=0.f,hA3=0.f;   // h1 accumulators (VGPR)

    for (int t = 0; t < T; ++t) {
        {
            AG16_LOAD(aA, s0, s1, s2, s3);
            l1cell(sm, tid, lw0, lw1, lw2, lb, s0, s1, s2, s3);
            AG16_STORE(aA, s0, s1, s2, s3);
        }
        {
            AG16_LOAD(aB, s0, s1, s2, s3);
            l1cell(sm, tid + 1024, lw0, lw1, lw2, lb, s0, s1, s2, s3);
            AG16_STORE(aB, s0, s1, s2, s3);
        }
        {
            AG16_LOAD(aC, s0, s1, s2, s3);
            l1cell(sm, tid + 2048, lw0, lw1, lw2, lb, s0, s1, s2, s3);
            AG16_STORE(aC, s0, s1, s2, s3);
        }
        if (tid < 3240 - 3072) {   // 168 overflow cells: LDS state, odd-stride
            float* cp = &sm[OFF_C1X + tid * 17];
            float4 s0 = make_float4(cp[0],  cp[1],  cp[2],  cp[3]);
            float4 s1 = make_float4(cp[4],  cp[5],  cp[6],  cp[7]);
            float4 s2 = make_float4(cp[8],  cp[9],  cp[10], cp[11]);
            float4 s3 = make_float4(cp[12], cp[13], cp[14], cp[15]);
            l1cell(sm, tid + 3072, lw0, lw1, lw2, lb, s0, s1, s2, s3);
            cp[0]=s0.x;  cp[1]=s0.y;  cp[2]=s0.z;  cp[3]=s0.w;
            cp[4]=s1.x;  cp[5]=s1.y;  cp[6]=s1.z;  cp[7]=s1.w;
            cp[8]=s2.x;  cp[9]=s2.y;  cp[10]=s2.z; cp[11]=s2.w;
            cp[12]=s3.x; cp[13]=s3.y; cp[14]=s3.z; cp[15]=s3.w;
        }
        __syncthreads();

        if (tid < 810) {
            AG16_LOAD(aP, s0, s1, s2, s3);
            l2cell(sm, tid, lw0, lw1, lw2, lb, s0, s1, s2, s3, hA0, hA1, hA2, hA3);
            AG16_STORE(aP, s0, s1, s2, s3);
        }
        __syncthreads();
    }

    // ---- epilogue: h1 -> LDS (overwrites S), FC(50x3240), task heads ----
    if (tid < 810)
        *reinterpret_cast<float4*>(&sm[OFF_S + tid * 4]) = make_float4(hA0, hA1, hA2, hA3);
    __syncthreads();

    float invT = 1.f / (float)T;
    int f = tid >> 4, g = tid & 15;
    if (f < 50) {
        const float* wrow = fc_w + f * 3240;
        float p0 = 0.f, p1 = 0.f;
        for (int j = g; j + 16 < 3240; j += 32) {
            p0 = fmaf(sm[OFF_S + j], wrow[j], p0);
            p1 = fmaf(sm[OFF_S + j + 16], wrow[j + 16], p1);
        }
        { int j = 3232 + g; if (j < 3240) p0 = fmaf(sm[OFF_S + j], wrow[j], p0); }
        float p = p0 + p1;
        p += __shfl_xor(p, 1);
        p += __shfl_xor(p, 2);
        p += __shfl_xor(p, 4);
        p += __shfl_xor(p, 8);
        if (g == 0) sm[OFF_X + f] = p * invT + fc_b[f];
    }
    __syncthreads();

    if (tid < 30) {
        float acc = task_b[tid];
        const float* twp = task_w + tid * 50;
        for (int j = 0; j < 50; ++j) acc = fmaf(sm[OFF_X + j], twp[j], acc);
        out[b * 30 + tid] = acc;
    }
}

extern "C" void kernel_launch(void* const* d_in, const int* in_sizes, int n_in,
                              void* d_out, int out_size, void* d_ws, size_t ws_size,
                              hipStream_t stream) {
    const float* x      = (const float*)d_in[0];
    const float* w1     = (const float*)d_in[1];
    const float* b1     = (const float*)d_in[2];
    const float* w2     = (const float*)d_in[3];
    const float* b2     = (const float*)d_in[4];
    const float* lif_w  = (const float*)d_in[5];
    const float* lif_b  = (const float*)d_in[6];
    const float* fc_w   = (const float*)d_in[7];
    const float* fc_b   = (const float*)d_in[8];
    const float* task_w = (const float*)d_in[9];
    const float* task_b = (const float*)d_in[10];
    const int*   tw     = (const int*)d_in[11];

    int B = in_sizes[0] / 1296;  // x is (B,1,36,36)

    scnn_kernel<<<B, 1024, 0, stream>>>(x, w1, b1, w2, b2, lif_w, lif_b,
                                        fc_w, fc_b, task_w, task_b, tw,
                                        (float*)d_out);
}

// Round 10
// 211.972 us; speedup vs baseline: 6.2994x; 1.1770x over previous
//
#include <hip/hip_runtime.h>

#define TH  0.3f
#define DEC 0.2f

// LDS layout (float offsets) — all 16B-aligned where vector-accessed
#define OFF_X    0        // 38*38 = 1444 (x, zero-padded border)
#define OFF_W1   1444     // 10*28 = 280  (repack: [oc][k*9+j], pad to 28)
#define OFF_B1   1724     // 30
#define OFF_W2   1756     // 100*28 = 2800 (repack: [oc][ic][k*9+j], pad 28)
#define OFF_B2   4556     // 30
#define OFF_LIF  4588     // 4
#define OFF_S    4592     // 10*20*20 = 4000 (pooled L1 spikes, padded border); h1 in epilogue
#define OFF_C1X  8592     // 168 overflow L1 cells x 17-float stride (bank-conflict-free)
#define OFF_C2   11448    // 810 L2 cells x 17-float stride (bank-conflict-free)
#define SMEM_N   25218    // 100,872 bytes

__device__ __forceinline__ float spikef(float v) { return v > TH ? 1.f : 0.f; }

// ---- AGPR residency: "=a"/"a" constraints pin values into the accum half
// of the unified register file (otherwise unused: no MFMA in this kernel).
__device__ __forceinline__ float ag_w(float v) {
    float a;
    asm("v_accvgpr_write_b32 %0, %1" : "=a"(a) : "v"(v));
    return a;
}
__device__ __forceinline__ float ag_r(float a) {
    float v;
    asm("v_accvgpr_read_b32 %0, %1" : "=v"(v) : "a"(a));
    return v;
}

#define AG16_DECL(P) \
    float P##0=ag_w(0.f), P##1=ag_w(0.f), P##2=ag_w(0.f), P##3=ag_w(0.f),   \
          P##4=ag_w(0.f), P##5=ag_w(0.f), P##6=ag_w(0.f), P##7=ag_w(0.f),   \
          P##8=ag_w(0.f), P##9=ag_w(0.f), P##10=ag_w(0.f), P##11=ag_w(0.f), \
          P##12=ag_w(0.f), P##13=ag_w(0.f), P##14=ag_w(0.f), P##15=ag_w(0.f)

// LIF update of one float4 state M (k0..k2 in x,y,z; hh-channel in w), drives D0..D2.
// inner_ computed from OLD mem (reference order).
#define LIF4(M, D0, D1, D2)                                            \
    {                                                                  \
        float inner_ = fmaf((M).x, lw0, fmaf((M).y, lw1, fmaf((M).z, lw2, lb))); \
        (M).x = ((M).x > TH ? 0.f : (M).x * DEC) + (D0);               \
        (M).y = ((M).y > TH ? 0.f : (M).y * DEC) + (D1);               \
        (M).z = ((M).z > TH ? 0.f : (M).z * DEC) + (D2);               \
        (M).w = ((M).w > TH ? 0.f : (M).w * DEC) + inner_;             \
    }

// stream 27 weights (float4 chunks, immediate consumption), ACC(k,r,c,w)
#define CONV27(WB, ACC)                                                      \
    do {                                                                     \
        float4 w4_;                                                          \
        _Pragma("unroll")                                                    \
        for (int j_ = 0; j_ < 27; ++j_) {                                    \
            if ((j_ & 3) == 0)                                               \
                w4_ = *reinterpret_cast<const float4*>(&sm[(WB) + j_]);      \
            const float wv_ = ((j_ & 3) == 0) ? w4_.x :                      \
                              ((j_ & 3) == 1) ? w4_.y :                      \
                              ((j_ & 3) == 2) ? w4_.z : w4_.w;               \
            const int k_ = j_ / 9, r_ = (j_ - k_ * 9) / 3,                   \
                      c_ = j_ - k_ * 9 - r_ * 3;                             \
            ACC(k_, r_, c_, wv_);                                            \
        }                                                                    \
    } while (0)

#define ACC_L1(K, R, C, W)                                   \
    d[0][K] = fmaf(xv[R][C],         (W), d[0][K]);          \
    d[1][K] = fmaf(xv[R][C + 1],     (W), d[1][K]);          \
    d[2][K] = fmaf(xv[R + 1][C],     (W), d[2][K]);          \
    d[3][K] = fmaf(xv[R + 1][C + 1], (W), d[3][K]);

#define ACC_L2(K, R, C, W)                                   \
    acc[0][K] = fmaf(sv[R][C],         (W), acc[0][K]);      \
    acc[1][K] = fmaf(sv[R][C + 1],     (W), acc[1][K]);      \
    acc[2][K] = fmaf(sv[R + 1][C],     (W), acc[2][K]);      \
    acc[3][K] = fmaf(sv[R + 1][C + 1], (W), acc[3][K]);

// ---- layer-1 conv drives only (no state touched) ----
__device__ __forceinline__ void conv1(const float* __restrict__ sm, int cell,
                                      float (&d)[4][3])
{
    int oc  = cell / 324;
    int rem = cell - oc * 324;
    int hh  = rem / 18;
    int ww  = rem - hh * 18;
    int y0 = 2 * hh, x0 = 2 * ww;

    float xv[4][4];
#pragma unroll
    for (int r = 0; r < 4; ++r) {
        float2 a = *reinterpret_cast<const float2*>(&sm[OFF_X + (y0 + r) * 38 + x0]);
        float2 b = *reinterpret_cast<const float2*>(&sm[OFF_X + (y0 + r) * 38 + x0 + 2]);
        xv[r][0] = a.x; xv[r][1] = a.y; xv[r][2] = b.x; xv[r][3] = b.y;
    }
    {
        float b0  = sm[OFF_B1 + oc];
        float b1v = sm[OFF_B1 + 10 + oc];
        float b2v = sm[OFF_B1 + 20 + oc];
#pragma unroll
        for (int p = 0; p < 4; ++p) { d[p][0] = b0; d[p][1] = b1v; d[p][2] = b2v; }
    }
    CONV27(OFF_W1 + oc * 28, ACC_L1);
}

// ---- layer-2 conv drives only ----
__device__ __forceinline__ void conv2(const float* __restrict__ sm, int cell,
                                      float (&acc)[4][3])
{
    int oc  = cell / 81;
    int rem = cell - oc * 81;
    int hh  = rem / 9;
    int ww  = rem - hh * 9;
    int y0 = 2 * hh, x0 = 2 * ww;

    {
        float b20 = 4.f * sm[OFF_B2 + oc];
        float b21 = 4.f * sm[OFF_B2 + 10 + oc];
        float b22 = 4.f * sm[OFF_B2 + 20 + oc];
#pragma unroll
        for (int p = 0; p < 4; ++p) { acc[p][0] = b20; acc[p][1] = b21; acc[p][2] = b22; }
    }

    const int sb = OFF_S + y0 * 20 + x0;
    const int wb = OFF_W2 + (oc * 10) * 28;

    for (int ic = 0; ic < 10; ++ic) {
        float sv[4][4];
#pragma unroll
        for (int r = 0; r < 4; ++r) {
            float2 a = *reinterpret_cast<const float2*>(&sm[sb + ic * 400 + r * 20]);
            float2 b = *reinterpret_cast<const float2*>(&sm[sb + ic * 400 + r * 20 + 2]);
            sv[r][0] = a.x; sv[r][1] = a.y; sv[r][2] = b.x; sv[r][3] = b.y;
        }
        CONV27(wb + ic * 28, ACC_L2);
    }
}

// one AGPR-resident L1 cell: conv first, then per-pixel LIF (only 4 state
// floats live in VGPRs at a time)
#define L1_AG_CELL(P, CELL)                                                   \
    {                                                                         \
        const int cell_ = (CELL);                                             \
        float d[4][3];                                                        \
        conv1(sm, cell_, d);                                                  \
        float ssum = 0.f; float4 m;                                           \
        m = make_float4(ag_r(P##0), ag_r(P##1), ag_r(P##2), ag_r(P##3));      \
        LIF4(m, d[0][0], d[0][1], d[0][2]);                                   \
        ssum += spikef(m.x) + spikef(m.y) + spikef(m.z) + spikef(m.w);        \
        P##0=ag_w(m.x); P##1=ag_w(m.y); P##2=ag_w(m.z); P##3=ag_w(m.w);       \
        m = make_float4(ag_r(P##4), ag_r(P##5), ag_r(P##6), ag_r(P##7));      \
        LIF4(m, d[1][0], d[1][1], d[1][2]);                                   \
        ssum += spikef(m.x) + spikef(m.y) + spikef(m.z) + spikef(m.w);        \
        P##4=ag_w(m.x); P##5=ag_w(m.y); P##6=ag_w(m.z); P##7=ag_w(m.w);       \
        m = make_float4(ag_r(P##8), ag_r(P##9), ag_r(P##10), ag_r(P##11));    \
        LIF4(m, d[2][0], d[2][1], d[2][2]);                                   \
        ssum += spikef(m.x) + spikef(m.y) + spikef(m.z) + spikef(m.w);        \
        P##8=ag_w(m.x); P##9=ag_w(m.y); P##10=ag_w(m.z); P##11=ag_w(m.w);     \
        m = make_float4(ag_r(P##12), ag_r(P##13), ag_r(P##14), ag_r(P##15));  \
        LIF4(m, d[3][0], d[3][1], d[3][2]);                                   \
        ssum += spikef(m.x) + spikef(m.y) + spikef(m.z) + spikef(m.w);        \
        P##12=ag_w(m.x); P##13=ag_w(m.y); P##14=ag_w(m.z); P##15=ag_w(m.w);   \
        int oc_ = cell_ / 324, rem_ = cell_ - oc_ * 324;                      \
        int hh_ = rem_ / 18, ww_ = rem_ - hh_ * 18;                           \
        sm[OFF_S + oc_ * 400 + (hh_ + 1) * 20 + (ww_ + 1)] = ssum * 0.25f;    \
    }

__attribute__((amdgpu_waves_per_eu(4, 4)))
__global__ __launch_bounds__(1024)
void scnn_kernel(const float* __restrict__ x,
                 const float* __restrict__ w1, const float* __restrict__ b1,
                 const float* __restrict__ w2, const float* __restrict__ b2,
                 const float* __restrict__ lif_w, const float* __restrict__ lif_b,
                 const float* __restrict__ fc_w, const float* __restrict__ fc_b,
                 const float* __restrict__ task_w, const float* __restrict__ task_b,
                 const int* __restrict__ tw_ptr,
                 float* __restrict__ out)
{
    __shared__ float sm[SMEM_N];
    const int tid = threadIdx.x;
    const int b   = blockIdx.x;
    const int T   = tw_ptr[0];

    for (int i = tid; i < SMEM_N; i += 1024) sm[i] = 0.f;
    __syncthreads();

    for (int i = tid; i < 1296; i += 1024) {
        int h = i / 36, w = i - h * 36;
        sm[OFF_X + (h + 1) * 38 + (w + 1)] = x[b * 1296 + i];
    }
    if (tid < 270) { // w1 (3,10,1,3,3) -> [oc][k*9+j] pad 28
        int k = tid / 90, r = tid - k * 90;
        int oc = r / 9, j = r - oc * 9;
        sm[OFF_W1 + oc * 28 + k * 9 + j] = w1[tid];
    }
    if (tid < 30)  sm[OFF_B1 + tid] = b1[tid];
    for (int i = tid; i < 2700; i += 1024) { // w2 (3,10,10,3,3) -> [oc][ic][k*9+j] pad 28
        int k = i / 900, r1 = i - k * 900;
        int oc = r1 / 90, r2 = r1 - oc * 90;
        int ic = r2 / 9,  j  = r2 - ic * 9;
        sm[OFF_W2 + (oc * 10 + ic) * 28 + k * 9 + j] = w2[i];
    }
    if (tid < 30)  sm[OFF_B2 + tid] = b2[tid];
    if (tid < 3)   sm[OFF_LIF + tid] = lif_w[tid];
    if (tid == 0)  sm[OFF_LIF + 3] = lif_b[0];
    __syncthreads();

    const float lw0 = sm[OFF_LIF + 0], lw1 = sm[OFF_LIF + 1],
                lw2 = sm[OFF_LIF + 2], lb  = sm[OFF_LIF + 3];

    // persistent AGPR state: 48 floats (3 L1 cells). L2 + overflow state in LDS.
    AG16_DECL(aA);   // L1 cell tid
    AG16_DECL(aB);   // L1 cell tid+1024
    AG16_DECL(aC);   // L1 cell tid+2048
    float hA0=0.f,hA1=0.f,hA2=0.f,hA3=0.f;   // h1 accumulators (VGPR)

    for (int t = 0; t < T; ++t) {
        L1_AG_CELL(aA, tid);
        __builtin_amdgcn_sched_barrier(0);
        L1_AG_CELL(aB, tid + 1024);
        __builtin_amdgcn_sched_barrier(0);
        L1_AG_CELL(aC, tid + 2048);
        __builtin_amdgcn_sched_barrier(0);
        if (tid < 3240 - 3072) {   // 168 overflow cells: LDS state, odd stride
            const int cell = tid + 3072;
            float d[4][3];
            conv1(sm, cell, d);
            float* cp = &sm[OFF_C1X + tid * 17];
            float ssum = 0.f;
#pragma unroll
            for (int p = 0; p < 4; ++p) {
                float4 m = make_float4(cp[4*p], cp[4*p+1], cp[4*p+2], cp[4*p+3]);
                LIF4(m, d[p][0], d[p][1], d[p][2]);
                ssum += spikef(m.x) + spikef(m.y) + spikef(m.z) + spikef(m.w);
                cp[4*p] = m.x; cp[4*p+1] = m.y; cp[4*p+2] = m.z; cp[4*p+3] = m.w;
            }
            int oc_ = cell / 324, rem_ = cell - oc_ * 324;
            int hh_ = rem_ / 18, ww_ = rem_ - hh_ * 18;
            sm[OFF_S + oc_ * 400 + (hh_ + 1) * 20 + (ww_ + 1)] = ssum * 0.25f;
        }
        __syncthreads();

        if (tid < 810) {           // L2: conv from S, state in LDS (odd stride)
            float acc[4][3];
            conv2(sm, tid, acc);
            float* cp = &sm[OFF_C2 + tid * 17];
#pragma unroll
            for (int p = 0; p < 4; ++p) {
                float4 m = make_float4(cp[4*p], cp[4*p+1], cp[4*p+2], cp[4*p+3]);
                LIF4(m, acc[p][0], acc[p][1], acc[p][2]);
                hA0 += spikef(m.x) * 0.25f; hA1 += spikef(m.y) * 0.25f;
                hA2 += spikef(m.z) * 0.25f; hA3 += spikef(m.w) * 0.25f;
                cp[4*p] = m.x; cp[4*p+1] = m.y; cp[4*p+2] = m.z; cp[4*p+3] = m.w;
            }
        }
        __syncthreads();
    }

    // ---- epilogue: h1 -> LDS (overwrites S), FC(50x3240), task heads ----
    if (tid < 810)
        *reinterpret_cast<float4*>(&sm[OFF_S + tid * 4]) = make_float4(hA0, hA1, hA2, hA3);
    __syncthreads();

    float invT = 1.f / (float)T;
    int f = tid >> 4, g = tid & 15;
    if (f < 50) {
        const float* wrow = fc_w + f * 3240;
        float p0 = 0.f, p1 = 0.f;
        for (int j = g; j + 16 < 3240; j += 32) {
            p0 = fmaf(sm[OFF_S + j], wrow[j], p0);
            p1 = fmaf(sm[OFF_S + j + 16], wrow[j + 16], p1);
        }
        { int j = 3232 + g; if (j < 3240) p0 = fmaf(sm[OFF_S + j], wrow[j], p0); }
        float p = p0 + p1;
        p += __shfl_xor(p, 1);
        p += __shfl_xor(p, 2);
        p += __shfl_xor(p, 4);
        p += __shfl_xor(p, 8);
        if (g == 0) sm[OFF_X + f] = p * invT + fc_b[f];
    }
    __syncthreads();

    if (tid < 30) {
        float acc = task_b[tid];
        const float* twp = task_w + tid * 50;
        for (int j = 0; j < 50; ++j) acc = fmaf(sm[OFF_X + j], twp[j], acc);
        out[b * 30 + tid] = acc;
    }
}

extern "C" void kernel_launch(void* const* d_in, const int* in_sizes, int n_in,
                              void* d_out, int out_size, void* d_ws, size_t ws_size,
                              hipStream_t stream) {
    const float* x      = (const float*)d_in[0];
    const float* w1     = (const float*)d_in[1];
    const float* b1     = (const float*)d_in[2];
    const float* w2     = (const float*)d_in[3];
    const float* b2     = (const float*)d_in[4];
    const float* lif_w  = (const float*)d_in[5];
    const float* lif_b  = (const float*)d_in[6];
    const float* fc_w   = (const float*)d_in[7];
    const float* fc_b   = (const float*)d_in[8];
    const float* task_w = (const float*)d_in[9];
    const float* task_b = (const float*)d_in[10];
    const int*   tw     = (const int*)d_in[11];

    int B = in_sizes[0] / 1296;  // x is (B,1,36,36)

    scnn_kernel<<<B, 1024, 0, stream>>>(x, w1, b1, w2, b2, lif_w, lif_b,
                                        fc_w, fc_b, task_w, task_b, tw,
                                        (float*)d_out);
}